// Round 4
// baseline (164.770 us; speedup 1.0000x reference)
//
#include <hip/hip_runtime.h>

// Camera back-projection R15b: R14 structure + NONTEMPORAL output stores.
// (R15 failed to compile: __builtin_nontemporal_store rejects the HIP
// wrapper float4*; cast through a native clang ext_vector_type(4) instead.)
//
// R13 (macro write ordering) and R14 (full-iz tile -> complete 2KB runs)
// both produced ZERO headline delta (158.4 -> 159.5 us, noise). Remaining
// untried write mechanism: L2 write-allocate pressure. Output stores dirty
// 16.8MB/XCD/iter through a 4MB per-XCD L2 -> the L2 cycles 4x with dirty
// evictions competing against the store stream AND evicting the depth
// images we pinned per-XCD. The output is write-once/streaming: store it
// nontemporal (global_store_dwordx4 ... nt), bypassing L2 dirty allocation.
//
// If this too leaves the headline at ~158, three independent write-path
// mechanisms all had no effect -> measured region is harness-fill-dominated
// (one ~80us 512MB poison fill per iteration + ~dozens of small resets) and
// the kernel is at its practical floor.
//
// Numerics (absmax 0.0 every round): exact IEEE '/' + rintf half-to-even in
// the reference's op order; U = ui<<2|uok<<15, V = vi*1920|vok<<31;
// offset = ((U&0x7FFF)+V)&0xFFFFF, valid = sign(V & U<<16); epilogue
// max(fma(-128,|zc-d|,1),0) == 1-128*min(|zc-d|,1/128) exactly; zc inline
// via exact fma; d>0 folds into the truncation branch (zc >= 1.70).

#define RES  128
#define IMG  480
#define US   136    // U slab row stride (ushorts)
#define VS   132    // V slab row stride (uints)

typedef float nfloat4 __attribute__((ext_vector_type(4)));   // native vec for nt store

__device__ __forceinline__ void compute_chunk(
    int C,
    float* __restrict__ r,
    const unsigned short* __restrict__ sU,
    const unsigned* __restrict__ sV,
    const char* __restrict__ dbase,
    float cd, int ix_l, int iy_l, int w)
{
#pragma unroll
    for (int g = 0; g < 2; ++g) {
        const int jq  = w * 2 + g;           // iz quad slot (0..7)
        const int izc = C * 32 + jq * 4;     // global iz of quad
        const ushort4 pu4 = *(const ushort4*)&sU[ix_l * US + izc];
        const uint4   pv4 = *(const uint4*)&sV[iy_l * VS + izc];
        const unsigned pua[4] = {pu4.x, pu4.y, pu4.z, pu4.w};
        const unsigned pva[4] = {pv4.x, pv4.y, pv4.z, pv4.w};
#pragma unroll
        for (int j = 0; j < 4; ++j) {
            const int   iz = izc + j;
            const float z  = fmaf((float)iz + 0.5f, 0.0078125f, -0.5f); // exact
            const float zc = cd - z;
            const unsigned off = ((pua[j] & 0x7FFFu) + pva[j]) & 0xFFFFFu;
            const float d  = *(const float*)(dbase + off);   // cache-hot gather
            const bool ok  = (int)(pva[j] & (pua[j] << 16)) < 0;
            const float v  = fmaxf(fmaf(-128.0f, fabsf(zc - d), 1.0f), 0.0f);
            r[g * 4 + j] = ok ? v : 0.0f;
        }
    }
}

__global__ __launch_bounds__(256, 4) void cbp_main(
    const float* __restrict__ depth, const float* __restrict__ fl,
    const float* __restrict__ cam_dist, float* __restrict__ out, int N)
{
    __shared__ __align__(16) float          s_tile[64 * 128]; // 32768 B swizzled
    __shared__ __align__(16) unsigned short s_U[16 * US];     // 4352 B
    __shared__ __align__(16) unsigned       s_V[4 * VS];      // 2112 B

    const int b = blockIdx.x;
    int n, rblk;
    if (N == 16) {                  // XCD-local: 2 depth images per XCD's L2
        const int xcd = b & 7, i = b >> 3;
        n = xcd * 2 + (i >> 8);
        rblk = i & 255;
    } else { n = b >> 8; rblk = b & 255; }
    const int ixg = rblk >> 5;      // 16-ix group (0..7)  -- slab-major order:
    const int iyg = rblk & 31;      // 4-iy group  (0..31) -- concurrent blocks
                                    //   tile ONE contiguous 1MB ix-slab
    const int l   = threadIdx.x;
    const float flv = fl[n];
    const float cd  = cam_dist[n];

    // ---- in-block tables: 10 exact IEEE divisions per thread ----
#pragma unroll
    for (int k = 0; k < 8; ++k) {   // U slab: 16 ix rows x 128 iz
        const int e   = l + 256 * k;
        const int row = e >> 7, izt = e & 127;
        const float zc = cd - ((izt + 0.5f) / 128.0f - 0.5f);
        const float x  = (ixg * 16 + row + 0.5f) / 128.0f - 0.5f;
        const float u  = (flv * x) / zc + 239.5f;            // exact IEEE div
        const int   ui = (int)fminf(fmaxf(rintf(u), 0.0f), 479.0f);
        const unsigned uok = (u >= 0.0f) && (u <= 479.0f);
        s_U[row * US + izt] = (unsigned short)((ui << 2) | (uok << 15));
    }
#pragma unroll
    for (int k = 0; k < 2; ++k) {   // V slab: 4 iy rows x 128 iz
        const int e   = l + 256 * k;
        const int iyt = e >> 7, izt = e & 127;
        const float zc = cd - ((izt + 0.5f) / 128.0f - 0.5f);
        const float y  = (iyg * 4 + iyt + 0.5f) / 128.0f - 0.5f;
        const float v  = (flv * y) / zc + 239.5f;            // exact IEEE div
        const int   vi = (int)fminf(fmaxf(rintf(v), 0.0f), 479.0f);
        const unsigned vok = (v >= 0.0f) && (v <= 479.0f) && (zc > 0.0f);
        s_V[iyt * VS + izt] = (unsigned)(vi * (IMG * 4)) | (vok << 31);
    }
    __syncthreads();

    const int ix_l = l & 15, iy_l = (l >> 4) & 3, w = l >> 6;
    const int trow = ix_l * 4 + iy_l;
    const char* __restrict__ dbase = (const char*)(depth + (size_t)n * (IMG * IMG));
    const size_t obase = ((size_t)((n << 7) + ixg * 16) << 7 | (iyg * 4)) << 7;

    // ---- compute all 128 iz barrier-free; stage into swizzled full tile ----
    float r[8];
#pragma unroll
    for (int c = 0; c < 4; ++c) {
        compute_chunk(c, r, s_U, s_V, dbase, cd, ix_l, iy_l, w);
        const int colb = c * 8 + w * 2;       // f4 column of this thread's quads
        *(float4*)&s_tile[(trow * 32 + ((colb    ) ^ (trow & 31))) * 4] =
            *(const float4*)&r[0];
        *(float4*)&s_tile[(trow * 32 + ((colb + 1) ^ (trow & 31))) * 4] =
            *(const float4*)&r[4];
    }
    __syncthreads();

    // ---- single store phase: wave = 1KB contiguous, NONTEMPORAL (L2 bypass);
    //      block = 16 x 2KB complete runs at 64KB stride ----
#pragma unroll
    for (int s = 0; s < 8; ++s) {
        const int g   = l + 256 * s;          // f4 index 0..2047
        const int tr  = g >> 5, col = g & 31;
        const nfloat4 val =
            *(const nfloat4*)&s_tile[(tr * 32 + (col ^ (tr & 31))) * 4];
        const int ix2 = tr >> 2, iy2 = tr & 3;
        __builtin_nontemporal_store(
            val,
            (nfloat4*)&out[obase + ((size_t)ix2 << 14) + (iy2 << 7) + (col << 2)]);
    }
}

extern "C" void kernel_launch(void* const* d_in, const int* in_sizes, int n_in,
                              void* d_out, int out_size, void* d_ws, size_t ws_size,
                              hipStream_t stream) {
    const float* depth = (const float*)d_in[0];
    const float* fl    = (const float*)d_in[1];
    const float* cd    = (const float*)d_in[2];
    float* out         = (float*)d_out;

    const int N = in_sizes[1];                     // fl is (N,1)
    cbp_main<<<N * 256, 256, 0, stream>>>(depth, fl, cd, out, N);
}

// Round 5
// 158.632 us; speedup vs baseline: 1.0387x; 1.0387x over previous
//
#include <hip/hip_runtime.h>

// Camera back-projection R16: revert to R14 (champion structure, plain
// stores). R15b's nontemporal stores were neutral-at-best: headline
// 159.5 -> 164.8 us, but the control (identical harness fills) slowed
// 80 -> 85 us the same round, explaining the delta entirely. Reverting the
// only change.
//
// Session evidence: three independent write-path mechanisms (R13 macro
// ordering, R14 complete-2KB-run granularity, R15b L2-bypass NT stores)
// all produced zero headline signal; top-5 dispatches every round are
// harness fills at 78-85% HBM peak; cbp_main is bounded < 80 us and never
// surfaces. The measured region is harness-fill-dominated; this kernel is
// at its practical floor. Expected: 158 +- 3 us, absmax 0.0.
//
// Structure (R14): full-iz 32KB swizzled LDS tile -> single store phase;
// every wave store is 1KB contiguous, every block emits 16 x 2KB COMPLETE
// row-groups at 64KB stride; slab-major rblk mapping keeps the ~32
// concurrent blocks of an XCD inside one contiguous 1MB ix-slab; tile is
// bank-swizzled (f4col ^ (row&31), b128 floor); LDS 38.3KB -> 4 blocks/CU,
// barrier-free compute phase pipelines all 32 gathers/thread.
//
// Numerics (absmax 0.0 every round): exact IEEE '/' + rintf half-to-even in
// the reference's op order; U = ui<<2|uok<<15, V = vi*1920|vok<<31;
// offset = ((U&0x7FFF)+V)&0xFFFFF, valid = sign(V & U<<16); epilogue
// max(fma(-128,|zc-d|,1),0) == 1-128*min(|zc-d|,1/128) exactly; zc inline
// via exact fma; d>0 folds into the truncation branch (zc >= 1.70).

#define RES  128
#define IMG  480
#define US   136    // U slab row stride (ushorts)
#define VS   132    // V slab row stride (uints)

__device__ __forceinline__ void compute_chunk(
    int C,
    float* __restrict__ r,
    const unsigned short* __restrict__ sU,
    const unsigned* __restrict__ sV,
    const char* __restrict__ dbase,
    float cd, int ix_l, int iy_l, int w)
{
#pragma unroll
    for (int g = 0; g < 2; ++g) {
        const int jq  = w * 2 + g;           // iz quad slot (0..7)
        const int izc = C * 32 + jq * 4;     // global iz of quad
        const ushort4 pu4 = *(const ushort4*)&sU[ix_l * US + izc];
        const uint4   pv4 = *(const uint4*)&sV[iy_l * VS + izc];
        const unsigned pua[4] = {pu4.x, pu4.y, pu4.z, pu4.w};
        const unsigned pva[4] = {pv4.x, pv4.y, pv4.z, pv4.w};
#pragma unroll
        for (int j = 0; j < 4; ++j) {
            const int   iz = izc + j;
            const float z  = fmaf((float)iz + 0.5f, 0.0078125f, -0.5f); // exact
            const float zc = cd - z;
            const unsigned off = ((pua[j] & 0x7FFFu) + pva[j]) & 0xFFFFFu;
            const float d  = *(const float*)(dbase + off);   // cache-hot gather
            const bool ok  = (int)(pva[j] & (pua[j] << 16)) < 0;
            const float v  = fmaxf(fmaf(-128.0f, fabsf(zc - d), 1.0f), 0.0f);
            r[g * 4 + j] = ok ? v : 0.0f;
        }
    }
}

__global__ __launch_bounds__(256, 4) void cbp_main(
    const float* __restrict__ depth, const float* __restrict__ fl,
    const float* __restrict__ cam_dist, float* __restrict__ out, int N)
{
    __shared__ __align__(16) float          s_tile[64 * 128]; // 32768 B swizzled
    __shared__ __align__(16) unsigned short s_U[16 * US];     // 4352 B
    __shared__ __align__(16) unsigned       s_V[4 * VS];      // 2112 B

    const int b = blockIdx.x;
    int n, rblk;
    if (N == 16) {                  // XCD-local: 2 depth images per XCD's L2
        const int xcd = b & 7, i = b >> 3;
        n = xcd * 2 + (i >> 8);
        rblk = i & 255;
    } else { n = b >> 8; rblk = b & 255; }
    const int ixg = rblk >> 5;      // 16-ix group (0..7)  -- slab-major order:
    const int iyg = rblk & 31;      // 4-iy group  (0..31) -- concurrent blocks
                                    //   tile ONE contiguous 1MB ix-slab
    const int l   = threadIdx.x;
    const float flv = fl[n];
    const float cd  = cam_dist[n];

    // ---- in-block tables: 10 exact IEEE divisions per thread ----
#pragma unroll
    for (int k = 0; k < 8; ++k) {   // U slab: 16 ix rows x 128 iz
        const int e   = l + 256 * k;
        const int row = e >> 7, izt = e & 127;
        const float zc = cd - ((izt + 0.5f) / 128.0f - 0.5f);
        const float x  = (ixg * 16 + row + 0.5f) / 128.0f - 0.5f;
        const float u  = (flv * x) / zc + 239.5f;            // exact IEEE div
        const int   ui = (int)fminf(fmaxf(rintf(u), 0.0f), 479.0f);
        const unsigned uok = (u >= 0.0f) && (u <= 479.0f);
        s_U[row * US + izt] = (unsigned short)((ui << 2) | (uok << 15));
    }
#pragma unroll
    for (int k = 0; k < 2; ++k) {   // V slab: 4 iy rows x 128 iz
        const int e   = l + 256 * k;
        const int iyt = e >> 7, izt = e & 127;
        const float zc = cd - ((izt + 0.5f) / 128.0f - 0.5f);
        const float y  = (iyg * 4 + iyt + 0.5f) / 128.0f - 0.5f;
        const float v  = (flv * y) / zc + 239.5f;            // exact IEEE div
        const int   vi = (int)fminf(fmaxf(rintf(v), 0.0f), 479.0f);
        const unsigned vok = (v >= 0.0f) && (v <= 479.0f) && (zc > 0.0f);
        s_V[iyt * VS + izt] = (unsigned)(vi * (IMG * 4)) | (vok << 31);
    }
    __syncthreads();

    const int ix_l = l & 15, iy_l = (l >> 4) & 3, w = l >> 6;
    const int trow = ix_l * 4 + iy_l;
    const char* __restrict__ dbase = (const char*)(depth + (size_t)n * (IMG * IMG));
    const size_t obase = ((size_t)((n << 7) + ixg * 16) << 7 | (iyg * 4)) << 7;

    // ---- compute all 128 iz barrier-free; stage into swizzled full tile ----
    float r[8];
#pragma unroll
    for (int c = 0; c < 4; ++c) {
        compute_chunk(c, r, s_U, s_V, dbase, cd, ix_l, iy_l, w);
        const int colb = c * 8 + w * 2;       // f4 column of this thread's quads
        *(float4*)&s_tile[(trow * 32 + ((colb    ) ^ (trow & 31))) * 4] =
            *(const float4*)&r[0];
        *(float4*)&s_tile[(trow * 32 + ((colb + 1) ^ (trow & 31))) * 4] =
            *(const float4*)&r[4];
    }
    __syncthreads();

    // ---- single store phase: wave = 1KB contiguous; block = 16 x 2KB runs ----
#pragma unroll
    for (int s = 0; s < 8; ++s) {
        const int g   = l + 256 * s;          // f4 index 0..2047
        const int tr  = g >> 5, col = g & 31;
        const float4 val =
            *(const float4*)&s_tile[(tr * 32 + (col ^ (tr & 31))) * 4];
        const int ix2 = tr >> 2, iy2 = tr & 3;
        *(float4*)&out[obase + ((size_t)ix2 << 14) + (iy2 << 7) + (col << 2)] = val;
    }
}

extern "C" void kernel_launch(void* const* d_in, const int* in_sizes, int n_in,
                              void* d_out, int out_size, void* d_ws, size_t ws_size,
                              hipStream_t stream) {
    const float* depth = (const float*)d_in[0];
    const float* fl    = (const float*)d_in[1];
    const float* cd    = (const float*)d_in[2];
    float* out         = (float*)d_out;

    const int N = in_sizes[1];                     // fl is (N,1)
    cbp_main<<<N * 256, 256, 0, stream>>>(depth, fl, cd, out, N);
}